// Round 2
// baseline (16143.813 us; speedup 1.0000x reference)
//
#include <hip/hip_runtime.h>
#include <hip/hip_cooperative_groups.h>
#include <math.h>

namespace cg = cooperative_groups;

#define BB 64
#define TT 32
#define II 512
#define HH 1024
#define OO 512
#define NN 1024
#define MM 64
#define SS 3
#define EPSF 1e-8f

struct P {
  const float *Wk_r,*bk_r,*Wb_r,*bb_r,*Wg_r,*bg_r,*Ws_r,*bs_r,*Wga_r,*bga_r;
  const float *Wk_w,*bk_w,*Wb_w,*bb_w,*Wg_w,*bg_w,*Ws_w,*bs_w,*Wga_w,*bga_w;
  const float *We,*be,*Wa,*ba,*W_r2i,*b_r2i,*Wih,*bih,*Whh,*bhh,*Who,*bho;
  const float *x;
  float *outs, *wr, *ww, *mem;
  float *kv, *beta, *g, *gamma, *s, *knorm, *e, *a, *xi;
  float *gi_part, *gh_part, *out_part;
};

__device__ __forceinline__ float sigmf(float x){ return 1.f/(1.f+expf(-x)); }
__device__ __forceinline__ float splusf(float x){ return fmaxf(x,0.f) + log1pf(expf(-fabsf(x))); }

// ---------- gates: 268 wave-dots over H=1024 for batch b ----------
__device__ void gates_phase(const P& p, const float* __restrict__ h, int b,
                            float* h_s, float (*kv_s)[MM], float (*sv_s)[SS]) {
  int t = threadIdx.x;
  ((float4*)h_s)[t] = ((const float4*)(h + (size_t)b*HH))[t];
  __syncthreads();
  int wv = t >> 6, lane = t & 63;
  for (int j = wv; j < 268; j += 4) {
    const float* Wrow = nullptr; float bias = 0.f; int act = 0;
    float* gdst = nullptr; int kvh = -1, kvm = 0, shh = -1, ssi = 0;
    if (j < 140) {
      int head = (j < 70) ? 0 : 1;
      int q = j - head*70;
      if (q < 64) {
        Wrow = (head ? p.Wk_w : p.Wk_r) + q*HH;
        bias = (head ? p.bk_w : p.bk_r)[q];
        act = 0; gdst = p.kv + (head*BB + b)*MM + q; kvh = head; kvm = q;
      } else if (q == 64) {
        Wrow = head ? p.Wb_w : p.Wb_r; bias = (head ? p.bb_w : p.bb_r)[0];
        act = 1; gdst = p.beta + head*BB + b;
      } else if (q == 65) {
        Wrow = head ? p.Wg_w : p.Wg_r; bias = (head ? p.bg_w : p.bg_r)[0];
        act = 2; gdst = p.g + head*BB + b;
      } else if (q < 69) {
        int i2 = q - 66;
        Wrow = (head ? p.Ws_w : p.Ws_r) + i2*HH; bias = (head ? p.bs_w : p.bs_r)[i2];
        act = 3; shh = head; ssi = i2;
      } else {
        Wrow = head ? p.Wga_w : p.Wga_r; bias = (head ? p.bga_w : p.bga_r)[0];
        act = 4; gdst = p.gamma + head*BB + b;
      }
    } else if (j < 204) {
      int m = j - 140; Wrow = p.We + m*HH; bias = p.be[m]; act = 2; gdst = p.e + b*MM + m;
    } else {
      int m = j - 204; Wrow = p.Wa + m*HH; bias = p.ba[m]; act = 0; gdst = p.a + b*MM + m;
    }
    float acc = 0.f;
    #pragma unroll
    for (int i = 0; i < 16; ++i) acc += Wrow[lane + 64*i] * h_s[lane + 64*i];
    #pragma unroll
    for (int off = 32; off; off >>= 1) acc += __shfl_down(acc, off);
    if (lane == 0) {
      float v = acc + bias;
      if (act == 0) v = tanhf(v);
      else if (act == 1) v = splusf(v);
      else if (act == 2) v = sigmf(v);
      else if (act == 4) v = 1.f + splusf(v);
      if (gdst) *gdst = v;
      if (kvh >= 0) kv_s[kvh][kvm] = v;
      if (shh >= 0) sv_s[shh][ssi] = v;
    }
  }
  __syncthreads();
  if (wv < 2) {
    float v = kv_s[wv][lane];
    float q = v * v;
    #pragma unroll
    for (int off = 32; off; off >>= 1) q += __shfl_down(q, off);
    if (lane == 0) p.knorm[wv*BB + b] = sqrtf(q);
  }
  if (t < 2) {
    int head = t;
    float a0 = sv_s[head][0], a1 = sv_s[head][1], a2 = sv_s[head][2];
    float mx = fmaxf(a0, fmaxf(a1, a2));
    float e0 = expf(a0-mx), e1 = expf(a1-mx), e2 = expf(a2-mx);
    float inv = 1.f/(e0+e1+e2);
    p.s[(head*BB + b)*SS + 0] = e0*inv;
    p.s[(head*BB + b)*SS + 1] = e1*inv;
    p.s[(head*BB + b)*SS + 2] = e2*inv;
  }
}

// ---------- 64x64 j/b tile, 256-wide K chunk split-K matmul item ----------
__device__ void mm_item(const float* __restrict__ in, const float* __restrict__ W,
                        float* __restrict__ part, int K, int Jtot, int jt, int kchunk,
                        float (*As)[68], float (*Bs)[68]) {
  int t = threadIdx.x;
  int k0base = kchunk * 256;
  int tb = (t & 15) * 4;
  int tj = (t >> 4) * 4;
  int lb = t >> 2;
  int lk = (t & 3) * 4;
  float a00=0,a01=0,a02=0,a03=0, a10=0,a11=0,a12=0,a13=0;
  float a20=0,a21=0,a22=0,a23=0, a30=0,a31=0,a32=0,a33=0;
  const float* inp = in + (size_t)lb*K + k0base + lk;
  const float* wp  = W  + (size_t)(jt + lb)*K + k0base + lk;
  for (int kc = 0; kc < 256; kc += 16) {
    float4 av = *(const float4*)(inp + kc);
    float4 wv = *(const float4*)(wp + kc);
    __syncthreads();
    As[lk+0][lb]=av.x; As[lk+1][lb]=av.y; As[lk+2][lb]=av.z; As[lk+3][lb]=av.w;
    Bs[lk+0][lb]=wv.x; Bs[lk+1][lb]=wv.y; Bs[lk+2][lb]=wv.z; Bs[lk+3][lb]=wv.w;
    __syncthreads();
    #pragma unroll
    for (int kk = 0; kk < 16; ++kk) {
      float4 a4 = *(const float4*)&As[kk][tb];
      float4 w4 = *(const float4*)&Bs[kk][tj];
      a00 += a4.x*w4.x; a01 += a4.x*w4.y; a02 += a4.x*w4.z; a03 += a4.x*w4.w;
      a10 += a4.y*w4.x; a11 += a4.y*w4.y; a12 += a4.y*w4.z; a13 += a4.y*w4.w;
      a20 += a4.z*w4.x; a21 += a4.z*w4.y; a22 += a4.z*w4.z; a23 += a4.z*w4.w;
      a30 += a4.w*w4.x; a31 += a4.w*w4.y; a32 += a4.w*w4.z; a33 += a4.w*w4.w;
    }
  }
  __syncthreads();
  size_t base = ((size_t)kchunk*BB + tb)*Jtot + jt + tj;
  float* d0 = part + base;
  d0[0]=a00; d0[1]=a01; d0[2]=a02; d0[3]=a03; d0 += Jtot;
  d0[0]=a10; d0[1]=a11; d0[2]=a12; d0[3]=a13; d0 += Jtot;
  d0[0]=a20; d0[1]=a21; d0[2]=a22; d0[3]=a23; d0 += Jtot;
  d0[0]=a30; d0[1]=a31; d0[2]=a32; d0[3]=a33;
}

// ---------- addressing per (head, b) ----------
__device__ void address_phase(const P& p, int b, int head,
                              float* k_s, float* wprev_s, float* pp, float* wg_s, float* red) {
  float* wbuf = head ? p.ww : p.wr;
  int t = threadIdx.x, wv = t >> 6, lane = t & 63;
  if (t < MM) k_s[t] = p.kv[(head*BB + b)*MM + t];
  for (int i = t; i < NN; i += 256) wprev_s[i] = wbuf[(size_t)b*NN + i];
  float beta = p.beta[head*BB + b];
  float g    = p.g[head*BB + b];
  float gam  = p.gamma[head*BB + b];
  float kn   = p.knorm[head*BB + b];
  float s0 = p.s[(head*BB + b)*SS + 0];
  float s1 = p.s[(head*BB + b)*SS + 1];
  float s2 = p.s[(head*BB + b)*SS + 2];
  __syncthreads();
  const float* memb = p.mem + (size_t)b*NN*MM;
  for (int n = wv; n < NN; n += 4) {
    float v = memb[(size_t)n*MM + lane];
    float d = k_s[lane]*v, q = v*v;
    #pragma unroll
    for (int off = 32; off; off >>= 1) { d += __shfl_down(d, off); q += __shfl_down(q, off); }
    if (lane == 0) pp[n] = beta * (d / (kn * sqrtf(q) + EPSF));
  }
  __syncthreads();
  float m = -1e30f;
  for (int i = t; i < NN; i += 256) m = fmaxf(m, pp[i]);
  red[t] = m; __syncthreads();
  for (int off = 128; off; off >>= 1) { if (t < off) red[t] = fmaxf(red[t], red[t+off]); __syncthreads(); }
  m = red[0]; __syncthreads();
  float sm = 0.f;
  for (int i = t; i < NN; i += 256) { float e = expf(pp[i]-m); pp[i] = e; sm += e; }
  red[t] = sm; __syncthreads();
  for (int off = 128; off; off >>= 1) { if (t < off) red[t] += red[t+off]; __syncthreads(); }
  float invs = 1.f/red[0]; __syncthreads();
  for (int i = t; i < NN; i += 256) wg_s[i] = g*(pp[i]*invs) + (1.f-g)*wprev_s[i];
  __syncthreads();
  float psum = 0.f;
  for (int i = t; i < NN; i += 256) {
    int im = (i == 0) ? NN-1 : i-1;
    int ip = (i == NN-1) ? 0 : i+1;
    float wt = s0*wg_s[im] + s1*wg_s[i] + s2*wg_s[ip];
    float w = powf(wt + 1e-12f, gam);
    pp[i] = w; psum += w;
  }
  red[t] = psum; __syncthreads();
  for (int off = 128; off; off >>= 1) { if (t < off) red[t] += red[t+off]; __syncthreads(); }
  float inv = 1.f/(red[0] + EPSF);
  for (int i = t; i < NN; i += 256) wbuf[(size_t)b*NN + i] = pp[i]*inv;
}

// ---------- fused read vector + mem erase/add + rin/xi ----------
__device__ void readmem_rinxi_phase(const P& p, int b, int tstep,
                                    float (*ea_s)[MM], float (*rp)[MM], float* r_s) {
  int t = threadIdx.x, wv = t >> 6, lane = t & 63;
  if (t < MM) { ea_s[0][t] = p.e[b*MM + t]; ea_s[1][t] = p.a[b*MM + t]; }
  __syncthreads();
  float racc = 0.f;
  float* memb = p.mem + (size_t)b*NN*MM;
  const float* wrb = p.wr + (size_t)b*NN;
  const float* wwb = p.ww + (size_t)b*NN;
  for (int n = wv; n < NN; n += 4) {
    float wrv = wrb[n], wwv = wwb[n];
    float v = memb[(size_t)n*MM + lane];
    racc += wrv * v;
    memb[(size_t)n*MM + lane] = v*(1.f - wwv*ea_s[0][lane]) + wwv*ea_s[1][lane];
  }
  rp[wv][lane] = racc;
  __syncthreads();
  if (t < MM) r_s[t] = rp[0][t]+rp[1][t]+rp[2][t]+rp[3][t];
  __syncthreads();
  for (int i = wv; i < II; i += 4) {
    float acc = r_s[lane] * p.W_r2i[(size_t)i*MM + lane];
    #pragma unroll
    for (int off = 32; off; off >>= 1) acc += __shfl_down(acc, off);
    if (lane == 0) {
      float rin = fmaxf(acc + p.b_r2i[i], 0.f);
      float xv = p.x[((size_t)b*TT + tstep)*II + i];
      p.xi[(size_t)b*II + i] = fmaxf(xv + rin, 0.f);
    }
  }
}

// ---------- GRU combine: 1 element/thread across 256 blocks ----------
__device__ void gru_phase(const P& p, const float* __restrict__ hold, float* __restrict__ hnew) {
  int idx = blockIdx.x*256 + threadIdx.x;      // < B*H (= 65536 exactly)
  int b = idx >> 10, j = idx & (HH-1);
  const size_t row = (size_t)b*3*HH;
  const float* gi = p.gi_part;
  const float* gh = p.gh_part;
  const size_t stride = (size_t)BB*3*HH;
  float ir = gi[row + j]        + gi[stride + row + j]        + p.bih[j];
  float iz = gi[row + j + HH]   + gi[stride + row + j + HH]   + p.bih[j + HH];
  float in_= gi[row + j + 2*HH] + gi[stride + row + j + 2*HH] + p.bih[j + 2*HH];
  float hr = gh[row + j]        + gh[stride + row + j]
           + gh[2*stride + row + j]        + gh[3*stride + row + j]        + p.bhh[j];
  float hz = gh[row + j + HH]   + gh[stride + row + j + HH]
           + gh[2*stride + row + j + HH]   + gh[3*stride + row + j + HH]   + p.bhh[j + HH];
  float hn = gh[row + j + 2*HH] + gh[stride + row + j + 2*HH]
           + gh[2*stride + row + j + 2*HH] + gh[3*stride + row + j + 2*HH] + p.bhh[j + 2*HH];
  float rr = sigmf(ir + hr);
  float zz = sigmf(iz + hz);
  float nn = tanhf(in_ + rr*hn);
  hnew[idx] = (1.f - zz)*nn + zz*hold[idx];
}

__device__ void out_final_phase(const P& p, int tstep, int blk128) {
  int idx = blk128*256 + threadIdx.x;          // < B*O (= 32768 exactly over 128 blocks)
  int b = idx >> 9, o = idx & (OO-1);
  float acc = p.bho[o];
  #pragma unroll
  for (int c = 0; c < 4; ++c) acc += p.out_part[((size_t)c*BB + b)*OO + o];
  p.outs[((size_t)b*TT + tstep)*OO + o] = sigmf(acc);
}

// ---------------- single cooperative kernel: all 32 steps ----------------
__global__ void __launch_bounds__(256) ntm_coop(P p, float* hA, float* hB) {
  cg::grid_group grid = cg::this_grid();
  __shared__ float h_s[HH];
  __shared__ float kv_s[2][MM];
  __shared__ float sv_s[2][SS];
  __shared__ float As[16][68];
  __shared__ float Bs[16][68];
  __shared__ float wprev_s[NN];
  __shared__ float pp[NN];
  __shared__ float wg_s[NN];
  __shared__ float red[256];
  __shared__ float k_s[MM];
  __shared__ float ea_s[2][MM];
  __shared__ float rp[4][MM];
  __shared__ float r_s[MM];

  int blk = blockIdx.x;
  for (int t = 0; t < TT; ++t) {
    const float* hc = (t & 1) ? hB : hA;
    float* hn = (t & 1) ? hA : hB;
    // Phase A: gates (0-63) || gh matmul (64-255) || prev-step out matmul (0-31)
    if (blk < 64) {
      gates_phase(p, hc, blk, h_s, kv_s, sv_s);
    } else {
      int idx = blk - 64;
      mm_item(hc, p.Whh, p.gh_part, HH, 3*HH, (idx % 48)*64, idx / 48, As, Bs);
    }
    if (t > 0 && blk < 32) {
      __syncthreads();
      mm_item(hc, p.Who, p.out_part, HH, OO, (blk % 8)*64, blk / 8, As, Bs);
    }
    grid.sync();
    // Phase B: addressing (0-127) || prev-step out finalize (128-255)
    if (blk < 128) {
      address_phase(p, blk >> 1, blk & 1, k_s, wprev_s, pp, wg_s, red);
    } else if (t > 0) {
      out_final_phase(p, t - 1, blk - 128);
    }
    grid.sync();
    // Phase C: read vector + mem update + rin/xi (0-63)
    if (blk < 64) readmem_rinxi_phase(p, blk, t, ea_s, rp, r_s);
    grid.sync();
    // Phase D: gi matmul (0-95)
    if (blk < 96) {
      mm_item(p.xi, p.Wih, p.gi_part, II, 3*HH, (blk % 48)*64, blk / 48, As, Bs);
    }
    grid.sync();
    // Phase E: GRU combine (all blocks)
    gru_phase(p, hc, hn);
    grid.sync();
  }
  // Epilogue: output for final step (h ends in hA after 32 steps)
  if (blk < 32) {
    mm_item(hA, p.Who, p.out_part, HH, OO, (blk % 8)*64, blk / 8, As, Bs);
  }
  grid.sync();
  if (blk < 128) out_final_phase(p, TT - 1, blk);
}

extern "C" void kernel_launch(void* const* d_in, const int* in_sizes, int n_in,
                              void* d_out, int out_size, void* d_ws, size_t ws_size,
                              hipStream_t stream) {
  const float* x    = (const float*)d_in[0];
  const float* h0   = (const float*)d_in[1];
  const float* wr0  = (const float*)d_in[2];
  const float* ww0  = (const float*)d_in[3];
  const float* mem0 = (const float*)d_in[4];
  P p;
  int i = 5;
  p.Wk_r  = (const float*)d_in[i++]; p.bk_r  = (const float*)d_in[i++];
  p.Wb_r  = (const float*)d_in[i++]; p.bb_r  = (const float*)d_in[i++];
  p.Wg_r  = (const float*)d_in[i++]; p.bg_r  = (const float*)d_in[i++];
  p.Ws_r  = (const float*)d_in[i++]; p.bs_r  = (const float*)d_in[i++];
  p.Wga_r = (const float*)d_in[i++]; p.bga_r = (const float*)d_in[i++];
  p.Wk_w  = (const float*)d_in[i++]; p.bk_w  = (const float*)d_in[i++];
  p.Wb_w  = (const float*)d_in[i++]; p.bb_w  = (const float*)d_in[i++];
  p.Wg_w  = (const float*)d_in[i++]; p.bg_w  = (const float*)d_in[i++];
  p.Ws_w  = (const float*)d_in[i++]; p.bs_w  = (const float*)d_in[i++];
  p.Wga_w = (const float*)d_in[i++]; p.bga_w = (const float*)d_in[i++];
  p.We    = (const float*)d_in[i++]; p.be    = (const float*)d_in[i++];
  p.Wa    = (const float*)d_in[i++]; p.ba    = (const float*)d_in[i++];
  p.W_r2i = (const float*)d_in[i++]; p.b_r2i = (const float*)d_in[i++];
  p.Wih   = (const float*)d_in[i++]; p.bih   = (const float*)d_in[i++];
  p.Whh   = (const float*)d_in[i++]; p.bhh   = (const float*)d_in[i++];
  p.Who   = (const float*)d_in[i++]; p.bho   = (const float*)d_in[i++];
  p.x = x;

  float* out = (float*)d_out;
  p.outs = out;                                  // (B,T,O)
  float* hOut = out + (size_t)BB*TT*OO;          // (B,H) final h
  p.wr  = hOut + (size_t)BB*HH;                  // (B,N) (R=1)
  p.ww  = p.wr + (size_t)BB*NN;                  // (B,N)
  p.mem = p.ww + (size_t)BB*NN;                  // (B,N,M)

  float* ws = (float*)d_ws;
  float* hAlt = ws;          ws += (size_t)BB*HH;
  p.kv       = ws;           ws += 2*BB*MM;
  p.beta     = ws;           ws += 2*BB;
  p.g        = ws;           ws += 2*BB;
  p.gamma    = ws;           ws += 2*BB;
  p.s        = ws;           ws += 2*BB*SS;
  p.knorm    = ws;           ws += 2*BB;
  p.e        = ws;           ws += BB*MM;
  p.a        = ws;           ws += BB*MM;
  p.xi       = ws;           ws += (size_t)BB*II;
  p.gi_part  = ws;           ws += (size_t)2*BB*3*HH;
  p.gh_part  = ws;           ws += (size_t)4*BB*3*HH;
  p.out_part = ws;           ws += (size_t)4*BB*OO;

  hipMemcpyAsync(hOut,  h0,   (size_t)BB*HH*sizeof(float),    hipMemcpyDeviceToDevice, stream);
  hipMemcpyAsync(p.wr,  wr0,  (size_t)BB*NN*sizeof(float),    hipMemcpyDeviceToDevice, stream);
  hipMemcpyAsync(p.ww,  ww0,  (size_t)BB*NN*sizeof(float),    hipMemcpyDeviceToDevice, stream);
  hipMemcpyAsync(p.mem, mem0, (size_t)BB*NN*MM*sizeof(float), hipMemcpyDeviceToDevice, stream);

  float* hA = hOut;
  float* hB = hAlt;
  void* args[] = { &p, &hA, &hB };
  hipLaunchCooperativeKernel((void*)ntm_coop, dim3(256), dim3(256), args, 0, stream);
}